// Round 9
// baseline (261.983 us; speedup 1.0000x reference)
//
#include <hip/hip_runtime.h>

#define LSEQ 512
#define RCA 3.8f

// Affine 4x4 with implicit bottom row (0,0,0,1), stored as 3x4.
struct Aff { float m[3][4]; };

__device__ __forceinline__ Aff compose(const Aff& A, const Aff& B) {
    Aff C;
#pragma unroll
    for (int i = 0; i < 3; ++i) {
#pragma unroll
        for (int j = 0; j < 4; ++j) {
            float v = A.m[i][0] * B.m[0][j] + A.m[i][1] * B.m[1][j] + A.m[i][2] * B.m[2][j];
            if (j == 3) v += A.m[i][3];
            C.m[i][j] = v;
        }
    }
    return C;
}

__device__ __forceinline__ Aff shflUp(const Aff& a, int d) {
    Aff r;
#pragma unroll
    for (int i = 0; i < 3; ++i)
#pragma unroll
        for (int j = 0; j < 4; ++j)
            r.m[i][j] = __shfl_up(a.m[i][j], d, 64);
    return r;
}

__device__ __forceinline__ Aff makeB(float ca, float sa, float cb, float sb) {
    Aff B;
    B.m[0][0] = ca;  B.m[0][1] = -sa * cb; B.m[0][2] =  sa * sb; B.m[0][3] = RCA * ca;
    B.m[1][0] = sa;  B.m[1][1] =  ca * cb; B.m[1][2] = -ca * sb; B.m[1][3] = RCA * sa;
    B.m[2][0] = 0.f; B.m[2][1] =  sb;      B.m[2][2] =  cb;      B.m[2][3] = 0.f;
    return B;
}

// One block (512 threads = 8 waves) per batch. Thread tid owns l = tid.
// F layout: F[((b*512+l)*24) + ch*12 + row*4 + col], ch=0 -> Fa, ch=1 -> Fb.
__global__ __launch_bounds__(512) void scan_kernel(const float* __restrict__ angles,
                                                   float* __restrict__ F) {
    const int b = blockIdx.x;
    const int tid = threadIdx.x;   // = l
    const int lane = tid & 63;
    const int w = tid >> 6;

    __shared__ float sT[8][12];    // per-wave inclusive totals

    const float a  = angles[(size_t)b * 1024 + tid];
    const float be = angles[(size_t)b * 1024 + 512 + tid];
    float sa, ca, sb, cb;
    __sincosf(a, &sa, &ca);
    __sincosf(be, &sb, &cb);

    // wave-inclusive scan of single matrices
    Aff S = makeB(ca, sa, cb, sb);
#pragma unroll
    for (int d = 1; d < 64; d <<= 1) {
        Aff o = shflUp(S, d);
        if (lane >= d) S = compose(o, S);
    }

    if (lane == 63) {
#pragma unroll
        for (int k = 0; k < 12; ++k) sT[w][k] = S.m[k / 4][k % 4];
    }
    __syncthreads();

    // exclusive cross-wave prefix E_w = T_0 @ ... @ T_{w-1}
    Aff E;
#pragma unroll
    for (int i = 0; i < 3; ++i)
#pragma unroll
        for (int j = 0; j < 4; ++j) E.m[i][j] = (i == j) ? 1.f : 0.f;
    for (int k = 0; k < w; ++k) {
        Aff T;
#pragma unroll
        for (int q = 0; q < 12; ++q) T.m[q / 4][q % 4] = sT[k][q];
        E = compose(E, T);
    }

    const Aff Sp = shflUp(S, 1);
    const Aff M = compose(E, S);                      // inclusive prefix at l
    Aff Mprev;
    if (lane == 0) Mprev = E;
    else           Mprev = compose(E, Sp);            // inclusive prefix at l-1

    // ---- epilogue: Fa/Fb = Mprev @ dB @ Minv ----
    float Rt[3][3], ti[3];
#pragma unroll
    for (int i = 0; i < 3; ++i)
#pragma unroll
        for (int j = 0; j < 3; ++j) Rt[i][j] = M.m[j][i];
#pragma unroll
    for (int i = 0; i < 3; ++i)
        ti[i] = -(M.m[0][i] * M.m[0][3] + M.m[1][i] * M.m[1][3] + M.m[2][i] * M.m[2][3]);

    float d0[4] = {-sa, -ca * cb,  ca * sb, -RCA * sa};
    float d1[4] = { ca, -sa * cb,  sa * sb,  RCA * ca};
    float e01 =  sa * sb, e02 =  sa * cb;
    float e11 = -ca * sb, e12 = -ca * cb;
    float e21 =  cb,      e22 = -sb;

    float Ga[3][4], Gb[3][4];
#pragma unroll
    for (int i = 0; i < 3; ++i) {
        float p0 = Mprev.m[i][0], p1 = Mprev.m[i][1], p2 = Mprev.m[i][2];
#pragma unroll
        for (int j = 0; j < 4; ++j) Ga[i][j] = p0 * d0[j] + p1 * d1[j];
        Gb[i][0] = 0.f;
        Gb[i][1] = p0 * e01 + p1 * e11 + p2 * e21;
        Gb[i][2] = p0 * e02 + p1 * e12 + p2 * e22;
        Gb[i][3] = 0.f;
    }

    float W[24];
#pragma unroll
    for (int i = 0; i < 3; ++i) {
#pragma unroll
        for (int j = 0; j < 3; ++j) {
            W[i * 4 + j]      = Ga[i][0] * Rt[0][j] + Ga[i][1] * Rt[1][j] + Ga[i][2] * Rt[2][j];
            W[12 + i * 4 + j] = Gb[i][0] * Rt[0][j] + Gb[i][1] * Rt[1][j] + Gb[i][2] * Rt[2][j];
        }
        W[i * 4 + 3]      = Ga[i][0] * ti[0] + Ga[i][1] * ti[1] + Ga[i][2] * ti[2] + Ga[i][3];
        W[12 + i * 4 + 3] = Gb[i][0] * ti[0] + Gb[i][1] * ti[1] + Gb[i][2] * ti[2] + Gb[i][3];
    }

    float4* w4 = reinterpret_cast<float4*>(F + ((size_t)b * LSEQ + tid) * 24);
    const float4* s4 = reinterpret_cast<const float4*>(W);
#pragma unroll
    for (int q = 0; q < 6; ++q) w4[q] = s4[q];
}

// grid (512, 32), block 256, no LDS, no barriers.
// Block (l, b) streams rows A and B (1539 floats each) as aligned float4 slots.
// Head/tail residue floats map to m=0 / m=512 which are always masked -> 0.
__global__ __launch_bounds__(256) void emit_direct(const float* __restrict__ F,
                                                   const float* __restrict__ coords,
                                                   const int* __restrict__ lens,
                                                   float* __restrict__ out) {
    const int l = blockIdx.x;
    const int b = blockIdx.y;
    const int t = threadIdx.x;

    // Block-uniform F row -> scalar loads.
    const float* __restrict__ f = F + ((size_t)b * LSEQ + l) * 24;
    float fc[24];
#pragma unroll
    for (int i = 0; i < 24; ++i) fc[i] = f[i];

    const unsigned len = (unsigned)lens[b];
    const unsigned lu = (unsigned)l;
    const bool rowActive = (lu < len);
    const float* __restrict__ cp = coords + (size_t)b * 1539;

    const size_t rbA = ((size_t)b * 1024 + l) * 1539;
    const size_t rbB = rbA + (size_t)LSEQ * 1539;
    const unsigned phase = (3u * lu) & 3u;
    const unsigned head = (4u - phase) & 3u;

    if (t == 255) {
        // head floats (m=0, masked) and tail floats (m=512, masked since len<=511)
        for (unsigned j = 0; j < head; ++j) { out[rbA + j] = 0.f; out[rbB + j] = 0.f; }
        const unsigned tail = (1539u - head) & 3u;
        for (unsigned j = 0; j < tail; ++j) { out[rbA + 1538u - j] = 0.f; out[rbB + 1538u - j] = 0.f; }
    }

    auto sel4 = [](const float* v, unsigned c) {   // c in {0,1,2} -> {v[c..c+3]}
        float4 r;
        r.x = (c == 0u) ? v[0] : ((c == 1u) ? v[1] : v[2]);
        r.y = (c == 0u) ? v[1] : ((c == 1u) ? v[2] : v[3]);
        r.z = (c == 0u) ? v[2] : ((c == 1u) ? v[3] : v[4]);
        r.w = (c == 0u) ? v[3] : ((c == 1u) ? v[4] : v[5]);
        return r;
    };

    auto doSlot = [&](unsigned k) {
        const unsigned off = head + 4u * k;         // float offset in row, (rb+off)%4==0
        const unsigned m0 = off / 3u;
        const unsigned c0 = off - 3u * m0;
        const unsigned m1 = m0 + 1u;
        const unsigned m1c = (m1 > 512u) ? 512u : m1;

        const float x0 = cp[m0 * 3u], y0 = cp[m0 * 3u + 1u], z0 = cp[m0 * 3u + 2u];
        const float x1 = cp[m1c * 3u], y1 = cp[m1c * 3u + 1u], z1 = cp[m1c * 3u + 2u];
        const float s0 = (rowActive && m0 > lu && m0 <= len) ? 1.f : 0.f;
        const float s1 = (rowActive && m1 > lu && m1 <= len) ? 1.f : 0.f;

        float vA[6], vB[6];
        vA[0] = s0 * (fc[0] * x0 + fc[1] * y0 + fc[2]  * z0 + fc[3]);
        vA[1] = s0 * (fc[4] * x0 + fc[5] * y0 + fc[6]  * z0 + fc[7]);
        vA[2] = s0 * (fc[8] * x0 + fc[9] * y0 + fc[10] * z0 + fc[11]);
        vA[3] = s1 * (fc[0] * x1 + fc[1] * y1 + fc[2]  * z1 + fc[3]);
        vA[4] = s1 * (fc[4] * x1 + fc[5] * y1 + fc[6]  * z1 + fc[7]);
        vA[5] = s1 * (fc[8] * x1 + fc[9] * y1 + fc[10] * z1 + fc[11]);
        vB[0] = s0 * (fc[12] * x0 + fc[13] * y0 + fc[14] * z0 + fc[15]);
        vB[1] = s0 * (fc[16] * x0 + fc[17] * y0 + fc[18] * z0 + fc[19]);
        vB[2] = s0 * (fc[20] * x0 + fc[21] * y0 + fc[22] * z0 + fc[23]);
        vB[3] = s1 * (fc[12] * x1 + fc[13] * y1 + fc[14] * z1 + fc[15]);
        vB[4] = s1 * (fc[16] * x1 + fc[17] * y1 + fc[18] * z1 + fc[19]);
        vB[5] = s1 * (fc[20] * x1 + fc[21] * y1 + fc[22] * z1 + fc[23]);

        *reinterpret_cast<float4*>(out + rbA + off) = sel4(vA, c0);
        *reinterpret_cast<float4*>(out + rbB + off) = sel4(vB, c0);
    };

    doSlot((unsigned)t);                            // slots 0..255
    if (t < 128) doSlot(256u + (unsigned)t);        // slots 256..383
}

extern "C" void kernel_launch(void* const* d_in, const int* in_sizes, int n_in,
                              void* d_out, int out_size, void* d_ws, size_t ws_size,
                              hipStream_t stream) {
    const float* angles = (const float*)d_in[0];   // fp32 (32, 2, 512)
    const float* coords = (const float*)d_in[1];   // fp32 (32, 1539)
    const int*   lens   = (const int*)d_in[2];     // int32 (32,)
    float* out = (float*)d_out;                    // fp32 output
    float* F = (float*)d_ws;                       // 32*512*24 fp32 = 1.57 MB scratch

    scan_kernel<<<32, 512, 0, stream>>>(angles, F);
    emit_direct<<<dim3(LSEQ, 32), 256, 0, stream>>>(F, coords, lens, out);
}

// Round 10
// 209.525 us; speedup vs baseline: 1.2504x; 1.2504x over previous
//
#include <hip/hip_runtime.h>

#define LSEQ 512
#define RCA 3.8f

// Affine 4x4 with implicit bottom row (0,0,0,1), stored as 3x4.
struct Aff { float m[3][4]; };

__device__ __forceinline__ Aff compose(const Aff& A, const Aff& B) {
    Aff C;
#pragma unroll
    for (int i = 0; i < 3; ++i) {
#pragma unroll
        for (int j = 0; j < 4; ++j) {
            float v = A.m[i][0] * B.m[0][j] + A.m[i][1] * B.m[1][j] + A.m[i][2] * B.m[2][j];
            if (j == 3) v += A.m[i][3];
            C.m[i][j] = v;
        }
    }
    return C;
}

__device__ __forceinline__ Aff shflUp(const Aff& a, int d) {
    Aff r;
#pragma unroll
    for (int i = 0; i < 3; ++i)
#pragma unroll
        for (int j = 0; j < 4; ++j)
            r.m[i][j] = __shfl_up(a.m[i][j], d, 64);
    return r;
}

__device__ __forceinline__ Aff makeB(float ca, float sa, float cb, float sb) {
    Aff B;
    B.m[0][0] = ca;  B.m[0][1] = -sa * cb; B.m[0][2] =  sa * sb; B.m[0][3] = RCA * ca;
    B.m[1][0] = sa;  B.m[1][1] =  ca * cb; B.m[1][2] = -ca * sb; B.m[1][3] = RCA * sa;
    B.m[2][0] = 0.f; B.m[2][1] =  sb;      B.m[2][2] =  cb;      B.m[2][3] = 0.f;
    return B;
}

// One block (512 threads = 8 waves) per batch. Thread tid owns l = tid.
// F layout: F[((b*512+l)*24) + ch*12 + row*4 + col], ch=0 -> Fa, ch=1 -> Fb.
__global__ __launch_bounds__(512) void scan_kernel(const float* __restrict__ angles,
                                                   float* __restrict__ F) {
    const int b = blockIdx.x;
    const int tid = threadIdx.x;   // = l
    const int lane = tid & 63;
    const int w = tid >> 6;

    __shared__ float sT[8][12];    // per-wave inclusive totals

    const float a  = angles[(size_t)b * 1024 + tid];
    const float be = angles[(size_t)b * 1024 + 512 + tid];
    float sa, ca, sb, cb;
    __sincosf(a, &sa, &ca);
    __sincosf(be, &sb, &cb);

    // wave-inclusive scan of single matrices
    Aff S = makeB(ca, sa, cb, sb);
#pragma unroll
    for (int d = 1; d < 64; d <<= 1) {
        Aff o = shflUp(S, d);
        if (lane >= d) S = compose(o, S);
    }

    if (lane == 63) {
#pragma unroll
        for (int k = 0; k < 12; ++k) sT[w][k] = S.m[k / 4][k % 4];
    }
    __syncthreads();

    // exclusive cross-wave prefix E_w = T_0 @ ... @ T_{w-1}
    Aff E;
#pragma unroll
    for (int i = 0; i < 3; ++i)
#pragma unroll
        for (int j = 0; j < 4; ++j) E.m[i][j] = (i == j) ? 1.f : 0.f;
    for (int k = 0; k < w; ++k) {
        Aff T;
#pragma unroll
        for (int q = 0; q < 12; ++q) T.m[q / 4][q % 4] = sT[k][q];
        E = compose(E, T);
    }

    const Aff Sp = shflUp(S, 1);
    const Aff M = compose(E, S);                      // inclusive prefix at l
    Aff Mprev;
    if (lane == 0) Mprev = E;
    else           Mprev = compose(E, Sp);            // inclusive prefix at l-1

    // ---- epilogue: Fa/Fb = Mprev @ dB @ Minv ----
    float Rt[3][3], ti[3];
#pragma unroll
    for (int i = 0; i < 3; ++i)
#pragma unroll
        for (int j = 0; j < 3; ++j) Rt[i][j] = M.m[j][i];
#pragma unroll
    for (int i = 0; i < 3; ++i)
        ti[i] = -(M.m[0][i] * M.m[0][3] + M.m[1][i] * M.m[1][3] + M.m[2][i] * M.m[2][3]);

    float d0[4] = {-sa, -ca * cb,  ca * sb, -RCA * sa};
    float d1[4] = { ca, -sa * cb,  sa * sb,  RCA * ca};
    float e01 =  sa * sb, e02 =  sa * cb;
    float e11 = -ca * sb, e12 = -ca * cb;
    float e21 =  cb,      e22 = -sb;

    float Ga[3][4], Gb[3][4];
#pragma unroll
    for (int i = 0; i < 3; ++i) {
        float p0 = Mprev.m[i][0], p1 = Mprev.m[i][1], p2 = Mprev.m[i][2];
#pragma unroll
        for (int j = 0; j < 4; ++j) Ga[i][j] = p0 * d0[j] + p1 * d1[j];
        Gb[i][0] = 0.f;
        Gb[i][1] = p0 * e01 + p1 * e11 + p2 * e21;
        Gb[i][2] = p0 * e02 + p1 * e12 + p2 * e22;
        Gb[i][3] = 0.f;
    }

    float W[24];
#pragma unroll
    for (int i = 0; i < 3; ++i) {
#pragma unroll
        for (int j = 0; j < 3; ++j) {
            W[i * 4 + j]      = Ga[i][0] * Rt[0][j] + Ga[i][1] * Rt[1][j] + Ga[i][2] * Rt[2][j];
            W[12 + i * 4 + j] = Gb[i][0] * Rt[0][j] + Gb[i][1] * Rt[1][j] + Gb[i][2] * Rt[2][j];
        }
        W[i * 4 + 3]      = Ga[i][0] * ti[0] + Ga[i][1] * ti[1] + Ga[i][2] * ti[2] + Ga[i][3];
        W[12 + i * 4 + 3] = Gb[i][0] * ti[0] + Gb[i][1] * ti[1] + Gb[i][2] * ti[2] + Gb[i][3];
    }

    float4* w4 = reinterpret_cast<float4*>(F + ((size_t)b * LSEQ + tid) * 24);
    const float4* s4 = reinterpret_cast<const float4*>(W);
#pragma unroll
    for (int q = 0; q < 6; ++q) w4[q] = s4[q];
}

// grid (32, 32), block 256. Block handles l = 16*bx .. 16*bx+15 for batch by.
// R5 structure (coords in registers, F via LDS, direct float3 stores),
// 16 rows/block to amortize the per-block prologue 4x harder.
__global__ __launch_bounds__(256) void emit_kernel(const float* __restrict__ F,
                                                   const float* __restrict__ coords,
                                                   const int* __restrict__ lens,
                                                   float* __restrict__ out) {
    const int b = blockIdx.y;
    const int l0 = blockIdx.x * 16;
    const int tid = threadIdx.x;

    __shared__ float sF[384];
    for (int i = tid; i < 384; i += 256) sF[i] = F[((size_t)b * LSEQ + l0) * 24 + i];

    const int len = lens[b];
    const float* cp = coords + (size_t)b * 1539;

    // preload coords for m = tid, tid+256, (tid+512 only for tid==0)
    const int m0 = tid, m1 = tid + 256, m2 = tid + 512;
    const float cx0 = cp[m0 * 3], cy0 = cp[m0 * 3 + 1], cz0 = cp[m0 * 3 + 2];
    const float cx1 = cp[m1 * 3], cy1 = cp[m1 * 3 + 1], cz1 = cp[m1 * 3 + 2];
    const bool has2 = (m2 < 513);
    float cx2 = 0.f, cy2 = 0.f, cz2 = 0.f;
    if (has2) { cx2 = cp[m2 * 3]; cy2 = cp[m2 * 3 + 1]; cz2 = cp[m2 * 3 + 2]; }

    __syncthreads();   // sF ready

#pragma unroll 1
    for (int i = 0; i < 16; ++i) {
        const int l = l0 + i;
        const float* f = sF + i * 24;
        const float f00 = f[0],  f01 = f[1],  f02 = f[2],  f03 = f[3];
        const float f10 = f[4],  f11 = f[5],  f12 = f[6],  f13 = f[7];
        const float f20 = f[8],  f21 = f[9],  f22 = f[10], f23 = f[11];
        const float g00 = f[12], g01 = f[13], g02 = f[14], g03 = f[15];
        const float g10 = f[16], g11 = f[17], g12 = f[18], g13 = f[19];
        const float g20 = f[20], g21 = f[21], g22 = f[22], g23 = f[23];

        const size_t baseA = ((size_t)(b * 2) * LSEQ + l) * 1539;
        const size_t baseB = baseA + (size_t)LSEQ * 1539;
        const bool rowActive = (l < len);

        auto emit1 = [&](int m, float x, float y, float z) {
            const float s = (rowActive && (m > l) && (m <= len)) ? 1.f : 0.f;
            float3 va, vb;
            va.x = s * (f00 * x + f01 * y + f02 * z + f03);
            va.y = s * (f10 * x + f11 * y + f12 * z + f13);
            va.z = s * (f20 * x + f21 * y + f22 * z + f23);
            vb.x = s * (g00 * x + g01 * y + g02 * z + g03);
            vb.y = s * (g10 * x + g11 * y + g12 * z + g13);
            vb.z = s * (g20 * x + g21 * y + g22 * z + g23);
            *reinterpret_cast<float3*>(out + baseA + (size_t)m * 3) = va;
            *reinterpret_cast<float3*>(out + baseB + (size_t)m * 3) = vb;
        };

        emit1(m0, cx0, cy0, cz0);
        emit1(m1, cx1, cy1, cz1);
        if (has2) emit1(m2, cx2, cy2, cz2);
    }
}

extern "C" void kernel_launch(void* const* d_in, const int* in_sizes, int n_in,
                              void* d_out, int out_size, void* d_ws, size_t ws_size,
                              hipStream_t stream) {
    const float* angles = (const float*)d_in[0];   // fp32 (32, 2, 512)
    const float* coords = (const float*)d_in[1];   // fp32 (32, 1539)
    const int*   lens   = (const int*)d_in[2];     // int32 (32,)
    float* out = (float*)d_out;                    // fp32 output
    float* F = (float*)d_ws;                       // 32*512*24 fp32 = 1.57 MB scratch

    scan_kernel<<<32, 512, 0, stream>>>(angles, F);
    emit_kernel<<<dim3(32, 32), 256, 0, stream>>>(F, coords, lens, out);
}